// Round 1
// baseline (62.962 us; speedup 1.0000x reference)
//
#include <hip/hip_runtime.h>
#include <stdint.h>

#define DIMS   4096
#define NT     256
#define EPT    16      // elements per thread
#define KSEL   16      // top-k per branch (KTOP/2)
#define CMAX   64      // candidate capacity (and search window upper bound)
#define ALPHA_C 6.26f

// exclusive index key: smaller element index -> larger ~idx -> ranked first among equal values
#define INVIDX(i) (~((((unsigned)((i) >> 2)) * 1024u) + (((unsigned)tid) << 2) + ((unsigned)((i) & 3))))

__device__ __forceinline__ unsigned block_reduce_u32(unsigned v, unsigned* red, unsigned* bc,
                                                     int lane, int wid, int tid) {
#pragma unroll
  for (int off = 32; off; off >>= 1) v += __shfl_down(v, off);
  if (lane == 0) red[wid] = v;
  __syncthreads();
  if (tid == 0) *bc = red[0] + red[1] + red[2] + red[3];
  __syncthreads();
  return *bc;
}

__global__ __launch_bounds__(NT, 4) void kcomp_kernel(const float* __restrict__ x,
                                                      float* __restrict__ out) {
  const int row  = blockIdx.x;
  const int tid  = threadIdx.x;
  const int lane = tid & 63;
  const int wid  = tid >> 6;

  __shared__ unsigned s_red[4];
  __shared__ unsigned s_bc;
  __shared__ float s_fred[2][4];
  __shared__ float s_sums[2];
  __shared__ unsigned long long s_cand[2][CMAX];
  __shared__ unsigned s_cnt[2];
  __shared__ unsigned long long s_T[2];
  __shared__ float s_add[2];

  const float4* xr = reinterpret_cast<const float4*>(x + (size_t)row * DIMS);

  unsigned kp[EPT], kn[EPT];
  float psum = 0.f, nsum = 0.f;

#pragma unroll
  for (int j = 0; j < 4; ++j) {
    float4 v = xr[j * NT + tid];
    float f[4] = {v.x, v.y, v.z, v.w};
#pragma unroll
    for (int c = 0; c < 4; ++c) {
      unsigned b  = __float_as_uint(f[c]);
      unsigned bp = (f[c] > 0.f) ? b : 0u;
      unsigned bn = (f[c] < 0.f) ? (b ^ 0x80000000u) : 0u;
      kp[j * 4 + c] = bp;
      kn[j * 4 + c] = bn;
      psum += __uint_as_float(bp);  // relu(x)
      nsum += __uint_as_float(bn);  // max(-x,0)
    }
  }

  // ---- row sums (block reduce) ----
  {
    float p = psum, n = nsum;
#pragma unroll
    for (int off = 32; off; off >>= 1) { p += __shfl_down(p, off); n += __shfl_down(n, off); }
    if (lane == 0) { s_fred[0][wid] = p; s_fred[1][wid] = n; }
  }
  __syncthreads();
  if (tid == 0) {
    s_sums[0] = s_fred[0][0] + s_fred[0][1] + s_fred[0][2] + s_fred[0][3];
    s_sums[1] = s_fred[1][0] + s_fred[1][1] + s_fred[1][2] + s_fred[1][3];
    s_cnt[0] = 0u; s_cnt[1] = 0u;
  }
  // visibility of s_sums/s_cnt guaranteed by the barriers inside the first reduce below

  // ---- stage 1: bisect a 32-bit key pivot so that count(key >= pivot) in [KSEL, CMAX] ----
  unsigned lo[2]  = {0u, 0u};
  unsigned hi[2]  = {0xFFFFFFFFu, 0xFFFFFFFFu};
  unsigned nlo[2] = {(unsigned)DIMS, (unsigned)DIMS};
  unsigned mid[2] = {0x40133333u, 0x40133333u};  // bits(2.3f): ~44 expected survivors
  bool done0 = false, done1 = false, st2_0 = false, st2_1 = false;

  for (int it = 0; it < 40 && !(done0 && done1); ++it) {
    unsigned c0 = 0, c1 = 0;
#pragma unroll
    for (int i = 0; i < EPT; ++i) {
      c0 += (kp[i] >= mid[0]) ? 1u : 0u;
      c1 += (kn[i] >= mid[1]) ? 1u : 0u;
    }
    unsigned tot = block_reduce_u32(c0 | (c1 << 16), s_red, &s_bc, lane, wid, tid);
    unsigned ns0 = tot & 0xFFFFu, ns1 = tot >> 16;

    if (!done0) {
      if (ns0 >= KSEL) { lo[0] = mid[0]; nlo[0] = ns0; if (ns0 <= CMAX) done0 = true; }
      else hi[0] = mid[0];
      if (!done0) {
        if (hi[0] - lo[0] <= 1u) { done0 = true; st2_0 = (nlo[0] > CMAX); }
        else mid[0] = lo[0] + ((hi[0] - lo[0]) >> 1);
      }
    }
    if (!done1) {
      if (ns1 >= KSEL) { lo[1] = mid[1]; nlo[1] = ns1; if (ns1 <= CMAX) done1 = true; }
      else hi[1] = mid[1];
      if (!done1) {
        if (hi[1] - lo[1] <= 1u) { done1 = true; st2_1 = (nlo[1] > CMAX); }
        else mid[1] = lo[1] + ((hi[1] - lo[1]) >> 1);
      }
    }
  }

  unsigned long long S0 = ((unsigned long long)lo[0]) << 32;
  unsigned long long S1 = ((unsigned long long)lo[1]) << 32;

  // ---- stage 2 (rare): >CMAX exact ties at the pivot -> bisect the packed-index word ----
  if (st2_0 | st2_1) {  // block-uniform
#pragma unroll
    for (int b = 0; b < 2; ++b) {
      bool active = b ? st2_1 : st2_0;
      if (!active) continue;  // uniform
      unsigned pivot = b ? lo[1] : lo[0];
      unsigned lo2 = 0u, hi2 = 0xFFFFFFFFu;
      unsigned nlo2 = b ? nlo[1] : nlo[0];
      for (int it = 0; it < 34 && nlo2 > CMAX; ++it) {
        unsigned mid2 = lo2 + ((hi2 - lo2) >> 1);
        unsigned c = 0;
#pragma unroll
        for (int i = 0; i < EPT; ++i) {
          unsigned k = b ? kn[i] : kp[i];
          c += ((k > pivot) || (k == pivot && INVIDX(i) >= mid2)) ? 1u : 0u;
        }
        unsigned n = block_reduce_u32(c, s_red, &s_bc, lane, wid, tid);
        if (n >= KSEL) { lo2 = mid2; nlo2 = n; } else hi2 = mid2;
        if (hi2 - lo2 <= 1u) break;  // uniqueness => nlo2 <= KSEL here
      }
      if (b) S1 = (((unsigned long long)pivot) << 32) | (unsigned long long)lo2;
      else   S0 = (((unsigned long long)pivot) << 32) | (unsigned long long)lo2;
    }
  }

  // ---- gather candidates (<= CMAX per branch) into LDS ----
#pragma unroll
  for (int i = 0; i < EPT; ++i) {
    unsigned long long Kp = (((unsigned long long)kp[i]) << 32) | (unsigned long long)INVIDX(i);
    if (Kp >= S0) { unsigned s = atomicAdd(&s_cnt[0], 1u); if (s < CMAX) s_cand[0][s] = Kp; }
    unsigned long long Kn = (((unsigned long long)kn[i]) << 32) | (unsigned long long)INVIDX(i);
    if (Kn >= S1) { unsigned s = atomicAdd(&s_cnt[1], 1u); if (s < CMAX) s_cand[1][s] = Kn; }
  }
  __syncthreads();

  // ---- exact top-16 per branch: wave 0 sorts pos candidates, wave 1 sorts neg ----
  if (wid < 2) {
    const int b = wid;
    unsigned n = s_cnt[b]; if (n > CMAX) n = CMAX;
    unsigned long long v = (lane < (int)n) ? s_cand[b][lane] : 0ULL;  // keys are unique and > 0
    // bitonic sort ascending across 64 lanes
#pragma unroll
    for (int k = 2; k <= 64; k <<= 1) {
#pragma unroll
      for (int j = k >> 1; j > 0; j >>= 1) {
        unsigned long long o = (unsigned long long)__shfl_xor((long long)v, j, 64);
        bool asc = ((lane & k) == 0);
        bool sm  = ((lane & j) == 0);
        unsigned long long mn = (v < o) ? v : o;
        unsigned long long mx = (v < o) ? o : v;
        v = (asc == sm) ? mn : mx;
      }
    }
    // top-16 now in lanes 48..63 (lane 48 = 16th largest = threshold)
    float val = __uint_as_float((unsigned)(v >> 32));
    float ts = val;
#pragma unroll
    for (int off = 1; off < 16; off <<= 1) ts += __shfl_xor(ts, off, 64);
    if (lane == 48) {
      s_T[b]   = v;
      s_add[b] = ALPHA_C * (s_sums[b] - ts);
    }
  }
  __syncthreads();

  // ---- emit: each thread writes back its own 16 elements (coalesced, no scatter) ----
  const unsigned long long T0 = s_T[0], T1 = s_T[1];
  const float a0 = s_add[0], a1 = s_add[1];
  float4* orow = reinterpret_cast<float4*>(out + (size_t)row * DIMS);
#pragma unroll
  for (int j = 0; j < 4; ++j) {
    float oc[4];
#pragma unroll
    for (int c = 0; c < 4; ++c) {
      const int i = j * 4 + c;
      unsigned long long Kp = (((unsigned long long)kp[i]) << 32) | (unsigned long long)INVIDX(i);
      unsigned long long Kn = (((unsigned long long)kn[i]) << 32) | (unsigned long long)INVIDX(i);
      float r = 0.f;
      if (Kp >= T0) r  = __uint_as_float(kp[i]) + a0;   // pv + p_tmp
      if (Kn >= T1) r -= __uint_as_float(kn[i]) + a1;   // -(nv + n_tmp)
      oc[c] = r;
    }
    float4 o; o.x = oc[0]; o.y = oc[1]; o.z = oc[2]; o.w = oc[3];
    orow[j * NT + tid] = o;
  }
}

extern "C" void kernel_launch(void* const* d_in, const int* in_sizes, int n_in,
                              void* d_out, int out_size, void* d_ws, size_t ws_size,
                              hipStream_t stream) {
  const float* x = (const float*)d_in[0];
  float* o = (float*)d_out;
  const int B = in_sizes[0] / DIMS;  // 8192
  hipLaunchKernelGGL(kcomp_kernel, dim3(B), dim3(NT), 0, stream, x, o);
}